// Round 8
// baseline (156.944 us; speedup 1.0000x reference)
//
#include <hip/hip_runtime.h>
#include <hip/hip_bf16.h>
#include <math.h>

#define N_NODES 50000
#define N_EDGES 600000
#define N_GRAPHS 512
#define LN_EPS 1e-5f
#define CAP 64
#define EDGE_BLOCKS ((N_EDGES / 4 + 255) / 256)
#define PREP_BLOCKS ((N_NODES * 64 + 255) / 256)

typedef short bf16x8 __attribute__((ext_vector_type(8)));
typedef float f32x4 __attribute__((ext_vector_type(4)));

__device__ __forceinline__ unsigned short f2bf(float f) {
    unsigned int x = __float_as_uint(f);
    return (unsigned short)((x + 0x7fffu + ((x >> 16) & 1u)) >> 16);
}
__device__ __forceinline__ float bflo(unsigned int u) { return __uint_as_float(u << 16); }
__device__ __forceinline__ float bfhi(unsigned int u) { return __uint_as_float(u & 0xffff0000u); }

// ---------------------------------------------------------------------------
__global__ __launch_bounds__(256) void zero_kernel(int* __restrict__ cnt)
{
    int i = blockIdx.x * 256 + threadIdx.x;
    if (i < N_NODES) cnt[i] = 0;
}

// ---------------------------------------------------------------------------
// fused: edge->padded-adjacency fill (ushort slots, 4 edges/thread)
//        + Xh1 build [N][64] + Wcat1 [128][128] + Wcat2 [128][256] + starts
__global__ __launch_bounds__(256) void prep_fill_kernel(
    const float* __restrict__ x, const float* __restrict__ xdims,
    const int* __restrict__ stt, const float* __restrict__ st_emb,
    const float* __restrict__ Wl1, const float* __restrict__ Wr1,
    const float* __restrict__ Wl2, const float* __restrict__ Wr2,
    const int* __restrict__ batch,
    const int* __restrict__ esrc_in, const int* __restrict__ edst_in,
    unsigned short* __restrict__ Xh1, unsigned short* __restrict__ Wc1,
    unsigned short* __restrict__ Wc2, int* __restrict__ cnt,
    unsigned short* __restrict__ adj, int* __restrict__ starts)
{
    if (blockIdx.x < EDGE_BLOCKS) {
        int t = blockIdx.x * 256 + threadIdx.x;
        int e4 = t * 4;
        if (e4 < N_EDGES) {
            int4 d4 = *(const int4*)(edst_in + e4);
            int4 s4 = *(const int4*)(esrc_in + e4);
            int sl0 = atomicAdd(&cnt[d4.x], 1);
            int sl1 = atomicAdd(&cnt[d4.y], 1);
            int sl2 = atomicAdd(&cnt[d4.z], 1);
            int sl3 = atomicAdd(&cnt[d4.w], 1);
            if (sl0 < CAP) adj[(size_t)d4.x * CAP + sl0] = (unsigned short)s4.x;
            if (sl1 < CAP) adj[(size_t)d4.y * CAP + sl1] = (unsigned short)s4.y;
            if (sl2 < CAP) adj[(size_t)d4.z * CAP + sl2] = (unsigned short)s4.z;
            if (sl3 < CAP) adj[(size_t)d4.w * CAP + sl3] = (unsigned short)s4.w;
        }
        return;
    }
    int idx = (blockIdx.x - EDGE_BLOCKS) * 256 + threadIdx.x;

    // job A: Xh1[n][c], c<44 data, 44..63 zero
    if (idx < N_NODES * 64) {
        int n = idx >> 6;
        int c = idx & 63;
        float v;
        if (c < 29)       v = x[n * 29 + c];
        else if (c < 32)  v = xdims[n * 3 + (c - 29)];
        else if (c < 44)  v = st_emb[stt[n] * 12 + (c - 32)];
        else              v = 0.f;
        Xh1[idx] = f2bf(v);
    }
    // job B: Wc1 row f = [Wr1(44) | 0x20 | Wl1(44) | 0x20]
    if (idx < 128 * 128) {
        int f = idx >> 7, k = idx & 127;
        float v;
        if (k < 44)        v = Wr1[f * 44 + k];
        else if (k < 64)   v = 0.f;
        else if (k < 108)  v = Wl1[f * 44 + (k - 64)];
        else               v = 0.f;
        Wc1[idx] = f2bf(v);
    }
    // job C: Wc2 row f = [Wr2(128) | Wl2(128)]
    if (idx < 128 * 256) {
        int f = idx >> 8, k = idx & 255;
        float v = (k < 128) ? Wr2[f * 128 + k] : Wl2[f * 128 + (k - 128)];
        Wc2[idx] = f2bf(v);
    }
    // job D: graph starts from sorted batch
    if (idx < N_NODES) {
        int b = batch[idx];
        int pb = (idx == 0) ? -1 : batch[idx - 1];
        for (int g = pb + 1; g <= b; ++g) starts[g] = idx;
        if (idx == N_NODES - 1)
            for (int g = b + 1; g <= N_GRAPHS; ++g) starts[g] = N_NODES;
    }
}

// ---------------------------------------------------------------------------
// fused layer: per wave, 16 nodes.
//   phase 1: neighbor-mean of its 16 nodes -> LDS (bf16, padded rows)
//   phase 2: MFMA  Out = relu(LN([h|mean] @ Wcat^T + bl))   (no barrier:
//            wave reads only its own 16 LDS rows)
// KPAD = 128 (layer1: DHALF=64) or 256 (layer2: DHALF=128)
template <int KPAD>
__global__ __launch_bounds__(256) void fused_layer_kernel(
    const int* __restrict__ cnt, const unsigned short* __restrict__ adj,
    const unsigned short* __restrict__ Xh,   // [N][DHALF] bf16 (gather + A h-half)
    const unsigned short* __restrict__ W,    // [128][KPAD]
    const float* __restrict__ bl, const float* __restrict__ g,
    const float* __restrict__ beta,
    unsigned short* __restrict__ Out)        // [N][128]
{
    constexpr int DHALF = KPAD / 2;
    constexpr int CH  = DHALF / 8;     // uint4 chunks per row (8 or 16)
    constexpr int NG  = 64 / CH;       // edge groups per wave (8 or 4)
    constexpr int NL  = 16 / NG;       // loads/lane per 16-edge iter (2 or 4)
    constexpr int RSU = CH + 1;        // LDS row stride in uint4 (+16B pad)
    __shared__ uint4 smean[64 * RSU];  // 64 rows per block (4 waves x 16)

    const int lane  = threadIdx.x & 63;
    const int wv    = threadIdx.x >> 6;
    const int nbase = blockIdx.x * 64 + wv * 16;

    // ---------------- phase 1: means -> LDS ----------------
    {
        const int grp = lane / CH;
        const int sl  = lane % CH;
        const uint4* gbase = (const uint4*)Xh;
        for (int i = 0; i < 16; ++i) {
            int n = nbase + i;
            if (n >= N_NODES) break;
            int degT = cnt[n];
            int deg  = (degT < CAP) ? degT : CAP;
            int er = adj[(size_t)n * CAP + lane];
            float a0=0.f,a1=0.f,a2=0.f,a3=0.f,a4=0.f,a5=0.f,a6=0.f,a7=0.f;
            const int c1 = deg - 1;
            for (int e = 0; e < deg; e += 16) {
                uint4 v[NL]; float mk[NL];
                #pragma unroll
                for (int j = 0; j < NL; ++j) {
                    int ee = e + j * NG + grp;
                    int s = __shfl(er, (ee < c1) ? ee : c1);
                    v[j]  = gbase[(size_t)s * CH + sl];
                    mk[j] = (ee < deg) ? 1.f : 0.f;
                }
                #pragma unroll
                for (int j = 0; j < NL; ++j) {
                    a0 += mk[j] * bflo(v[j].x); a1 += mk[j] * bfhi(v[j].x);
                    a2 += mk[j] * bflo(v[j].y); a3 += mk[j] * bfhi(v[j].y);
                    a4 += mk[j] * bflo(v[j].z); a5 += mk[j] * bfhi(v[j].z);
                    a6 += mk[j] * bflo(v[j].w); a7 += mk[j] * bfhi(v[j].w);
                }
            }
            #pragma unroll
            for (int m = CH; m <= 32; m <<= 1) {
                a0 += __shfl_xor(a0, m); a1 += __shfl_xor(a1, m);
                a2 += __shfl_xor(a2, m); a3 += __shfl_xor(a3, m);
                a4 += __shfl_xor(a4, m); a5 += __shfl_xor(a5, m);
                a6 += __shfl_xor(a6, m); a7 += __shfl_xor(a7, m);
            }
            if (grp == 0) {
                float inv = (degT > 0) ? 1.f / (float)degT : 0.f;
                uint4 p;
                p.x = (unsigned int)f2bf(a0 * inv) | ((unsigned int)f2bf(a1 * inv) << 16);
                p.y = (unsigned int)f2bf(a2 * inv) | ((unsigned int)f2bf(a3 * inv) << 16);
                p.z = (unsigned int)f2bf(a4 * inv) | ((unsigned int)f2bf(a5 * inv) << 16);
                p.w = (unsigned int)f2bf(a6 * inv) | ((unsigned int)f2bf(a7 * inv) << 16);
                smean[(size_t)(wv * 16 + i) * RSU + sl] = p;
            }
        }
    }

    // ---------------- phase 2: MFMA + LN + relu ----------------
    const int l15 = lane & 15;
    const int l4  = lane >> 4;
    int rA = nbase + l15; if (rA > N_NODES - 1) rA = N_NODES - 1;

    f32x4 acc[8];
    #pragma unroll
    for (int n = 0; n < 8; ++n) acc[n] = (f32x4){0.f, 0.f, 0.f, 0.f};

    const int kb = l4 * 8;
    const unsigned short* sm = (const unsigned short*)smean;
    #pragma unroll
    for (int ks = 0; ks < KPAD / 32; ++ks) {
        const int k = ks * 32 + kb;
        bf16x8 a;
        if (ks < KPAD / 64) {   // compile-time: h half from global
            a = *(const bf16x8*)(Xh + (size_t)rA * DHALF + k);
        } else {                // mean half from this wave's LDS rows
            a = *(const bf16x8*)(sm + (size_t)(wv * 16 + l15) * RSU * 8 + (k - DHALF));
        }
        #pragma unroll
        for (int ni = 0; ni < 8; ++ni) {
            bf16x8 b = *(const bf16x8*)(W + (size_t)(ni * 16 + l15) * KPAD + k);
            acc[ni] = __builtin_amdgcn_mfma_f32_16x16x32_bf16(a, b, acc[ni], 0, 0, 0);
        }
    }

    float blv[8], gv[8], bev[8];
    #pragma unroll
    for (int ni = 0; ni < 8; ++ni) {
        int f = ni * 16 + l15;
        blv[ni] = bl[f]; gv[ni] = g[f]; bev[ni] = beta[f];
    }

    #pragma unroll
    for (int r = 0; r < 4; ++r) {
        float v[8];
        float s1 = 0.f, s2 = 0.f;
        #pragma unroll
        for (int ni = 0; ni < 8; ++ni) {
            float t = acc[ni][r] + blv[ni];
            v[ni] = t; s1 += t; s2 += t * t;
        }
        #pragma unroll
        for (int m = 8; m >= 1; m >>= 1) {
            s1 += __shfl_xor(s1, m);
            s2 += __shfl_xor(s2, m);
        }
        float mu   = s1 * (1.f / 128.f);
        float var  = s2 * (1.f / 128.f) - mu * mu;
        float rstd = rsqrtf(var + LN_EPS);
        int node = nbase + l4 * 4 + r;
        if (node < N_NODES) {
            #pragma unroll
            for (int ni = 0; ni < 8; ++ni) {
                float o = gv[ni] * (v[ni] - mu) * rstd + bev[ni];
                o = fmaxf(o, 0.f);
                Out[(size_t)node * 128 + ni * 16 + l15] = f2bf(o);
            }
        }
    }
}

// ---------------------------------------------------------------------------
// fused pooling (mean+max) + linear head. 1 block / graph, 256 threads.
__global__ __launch_bounds__(256) void poolhead_kernel(const unsigned short* __restrict__ h2,
                                                       const int* __restrict__ starts,
                                                       const float* __restrict__ Wlin,
                                                       const float* __restrict__ blin,
                                                       float* __restrict__ out)
{
    const int g  = blockIdx.x;
    const int j2 = threadIdx.x & 63;   // col pair 2*j2, 2*j2+1
    const int h  = threadIdx.x >> 6;   // row group 0..3
    const int s0 = starts[g], s1 = starts[g + 1];
    float sa = 0.f, sb = 0.f, ma = -INFINITY, mb = -INFINITY;
    const unsigned int* base = (const unsigned int*)h2;   // row stride 64 uints
    int n = s0 + h;
    for (; n + 4 < s1; n += 8) {
        unsigned int u0 = base[(size_t)n * 64 + j2];
        unsigned int u1 = base[(size_t)(n + 4) * 64 + j2];
        float l0 = bflo(u0), h0 = bfhi(u0);
        float l1 = bflo(u1), h1 = bfhi(u1);
        sa += l0 + l1; sb += h0 + h1;
        ma = fmaxf(ma, fmaxf(l0, l1));
        mb = fmaxf(mb, fmaxf(h0, h1));
    }
    if (n < s1) {
        unsigned int u = base[(size_t)n * 64 + j2];
        float lo = bflo(u), hi = bfhi(u);
        sa += lo; sb += hi;
        ma = fmaxf(ma, lo); mb = fmaxf(mb, hi);
    }
    __shared__ float red[4][4][64];
    __shared__ float pooled[256];
    red[h][0][j2] = sa; red[h][1][j2] = sb; red[h][2][j2] = ma; red[h][3][j2] = mb;
    __syncthreads();
    if (h == 0) {
        #pragma unroll
        for (int o = 1; o < 4; ++o) {
            sa += red[o][0][j2]; sb += red[o][1][j2];
            ma = fmaxf(ma, red[o][2][j2]); mb = fmaxf(mb, red[o][3][j2]);
        }
        int c = s1 - s0;
        float inv = (c > 0) ? 1.f / (float)c : 0.f;
        pooled[2 * j2]           = sa * inv;
        pooled[2 * j2 + 1]       = sb * inv;
        pooled[128 + 2 * j2]     = (c > 0) ? ma : 0.f;
        pooled[128 + 2 * j2 + 1] = (c > 0) ? mb : 0.f;
    }
    __syncthreads();
    if (threadIdx.x < 10) {
        const float* w = Wlin + threadIdx.x * 256;
        float acc = blin[threadIdx.x];
        for (int k = 0; k < 256; ++k) acc += pooled[k] * w[k];
        out[g * 10 + threadIdx.x] = acc;
    }
}

// ---------------------------------------------------------------------------
extern "C" void kernel_launch(void* const* d_in, const int* in_sizes, int n_in,
                              void* d_out, int out_size, void* d_ws, size_t ws_size,
                              hipStream_t stream)
{
    const float* x      = (const float*)d_in[0];
    const float* xdims  = (const float*)d_in[1];
    const int*   stt    = (const int*)d_in[2];
    const int*   eidx   = (const int*)d_in[3];
    const int*   batch  = (const int*)d_in[4];
    const float* st_emb = (const float*)d_in[5];
    const float* Wl1 = (const float*)d_in[6];
    const float* bl1 = (const float*)d_in[7];
    const float* Wr1 = (const float*)d_in[8];
    const float* g1  = (const float*)d_in[9];
    const float* be1 = (const float*)d_in[10];
    const float* Wl2 = (const float*)d_in[11];
    const float* bl2 = (const float*)d_in[12];
    const float* Wr2 = (const float*)d_in[13];
    const float* g2  = (const float*)d_in[14];
    const float* be2 = (const float*)d_in[15];
    const float* Wlin = (const float*)d_in[16];
    const float* blin = (const float*)d_in[17];
    float* out = (float*)d_out;

    const int* esrc_in = eidx;
    const int* edst_in = eidx + N_EDGES;

    char* ws = (char*)d_ws;
    size_t o = 0;
    auto carve = [&](size_t bytes) { void* p = ws + o; o = (o + bytes + 255) & ~(size_t)255; return p; };
    unsigned short* Xh1  = (unsigned short*)carve((size_t)N_NODES * 64 * 2);
    unsigned short* Xh2  = (unsigned short*)carve((size_t)N_NODES * 128 * 2);
    unsigned short* h2bf = (unsigned short*)carve((size_t)N_NODES * 128 * 2);
    unsigned short* Wc1  = (unsigned short*)carve((size_t)128 * 128 * 2);
    unsigned short* Wc2  = (unsigned short*)carve((size_t)128 * 256 * 2);
    int*            cnt  = (int*)carve((size_t)N_NODES * 4);
    unsigned short* adj  = (unsigned short*)carve((size_t)N_NODES * CAP * 2);
    int*          starts = (int*)carve((size_t)(N_GRAPHS + 1) * 4);
    (void)ws_size;

    // 1. zero degree counters
    zero_kernel<<<(N_NODES + 255) / 256, 256, 0, stream>>>(cnt);

    // 2. fused edge fill + Xh1 + weight concat + graph starts
    prep_fill_kernel<<<EDGE_BLOCKS + PREP_BLOCKS, 256, 0, stream>>>(
        x, xdims, stt, st_emb, Wl1, Wr1, Wl2, Wr2, batch,
        esrc_in, edst_in, Xh1, Wc1, Wc2, cnt, adj, starts);

    // 3. layer 1 (agg + GEMM fused)
    fused_layer_kernel<128><<<(N_NODES + 63) / 64, 256, 0, stream>>>(
        cnt, adj, Xh1, Wc1, bl1, g1, be1, Xh2);

    // 4. layer 2 (agg + GEMM fused)
    fused_layer_kernel<256><<<(N_NODES + 63) / 64, 256, 0, stream>>>(
        cnt, adj, Xh2, Wc2, bl2, g2, be2, h2bf);

    // 5. fused pooling + head
    poolhead_kernel<<<N_GRAPHS, 256, 0, stream>>>(h2bf, starts, Wlin, blin, out);
}

// Round 9
// 135.369 us; speedup vs baseline: 1.1594x; 1.1594x over previous
//
#include <hip/hip_runtime.h>
#include <hip/hip_bf16.h>
#include <math.h>

#define N_NODES 50000
#define N_EDGES 600000
#define N_GRAPHS 512
#define LN_EPS 1e-5f
#define CAP 64
#define EDGE_BLOCKS ((N_EDGES / 4 + 255) / 256)
#define PREP_BLOCKS ((N_NODES * 64 + 255) / 256)

typedef short bf16x8 __attribute__((ext_vector_type(8)));
typedef float f32x4 __attribute__((ext_vector_type(4)));

__device__ __forceinline__ unsigned short f2bf(float f) {
    unsigned int x = __float_as_uint(f);
    return (unsigned short)((x + 0x7fffu + ((x >> 16) & 1u)) >> 16);
}
__device__ __forceinline__ float bflo(unsigned int u) { return __uint_as_float(u << 16); }
__device__ __forceinline__ float bfhi(unsigned int u) { return __uint_as_float(u & 0xffff0000u); }

// ---------------------------------------------------------------------------
__global__ __launch_bounds__(256) void zero_kernel(int* __restrict__ cnt)
{
    int i = blockIdx.x * 256 + threadIdx.x;
    if (i < N_NODES) cnt[i] = 0;
}

// ---------------------------------------------------------------------------
// fused: edge->padded-adjacency fill (ushort slots, 4 edges/thread)
//        + Xh1 build [N][64] + Wcat1 [128][128] + Wcat2 [128][256] + starts
__global__ __launch_bounds__(256) void prep_fill_kernel(
    const float* __restrict__ x, const float* __restrict__ xdims,
    const int* __restrict__ stt, const float* __restrict__ st_emb,
    const float* __restrict__ Wl1, const float* __restrict__ Wr1,
    const float* __restrict__ Wl2, const float* __restrict__ Wr2,
    const int* __restrict__ batch,
    const int* __restrict__ esrc_in, const int* __restrict__ edst_in,
    unsigned short* __restrict__ Xh1, unsigned short* __restrict__ Wc1,
    unsigned short* __restrict__ Wc2, int* __restrict__ cnt,
    unsigned short* __restrict__ adj, int* __restrict__ starts)
{
    if (blockIdx.x < EDGE_BLOCKS) {
        int t = blockIdx.x * 256 + threadIdx.x;
        int e4 = t * 4;
        if (e4 < N_EDGES) {
            int4 d4 = *(const int4*)(edst_in + e4);
            int4 s4 = *(const int4*)(esrc_in + e4);
            int sl0 = atomicAdd(&cnt[d4.x], 1);
            int sl1 = atomicAdd(&cnt[d4.y], 1);
            int sl2 = atomicAdd(&cnt[d4.z], 1);
            int sl3 = atomicAdd(&cnt[d4.w], 1);
            if (sl0 < CAP) adj[(size_t)d4.x * CAP + sl0] = (unsigned short)s4.x;
            if (sl1 < CAP) adj[(size_t)d4.y * CAP + sl1] = (unsigned short)s4.y;
            if (sl2 < CAP) adj[(size_t)d4.z * CAP + sl2] = (unsigned short)s4.z;
            if (sl3 < CAP) adj[(size_t)d4.w * CAP + sl3] = (unsigned short)s4.w;
        }
        return;
    }
    int idx = (blockIdx.x - EDGE_BLOCKS) * 256 + threadIdx.x;

    // job A: Xh1[n][c], c<44 data, 44..63 zero
    if (idx < N_NODES * 64) {
        int n = idx >> 6;
        int c = idx & 63;
        float v;
        if (c < 29)       v = x[n * 29 + c];
        else if (c < 32)  v = xdims[n * 3 + (c - 29)];
        else if (c < 44)  v = st_emb[stt[n] * 12 + (c - 32)];
        else              v = 0.f;
        Xh1[idx] = f2bf(v);
    }
    // job B: Wc1 row f = [Wr1(44) | 0x20 | Wl1(44) | 0x20]
    if (idx < 128 * 128) {
        int f = idx >> 7, k = idx & 127;
        float v;
        if (k < 44)        v = Wr1[f * 44 + k];
        else if (k < 64)   v = 0.f;
        else if (k < 108)  v = Wl1[f * 44 + (k - 64)];
        else               v = 0.f;
        Wc1[idx] = f2bf(v);
    }
    // job C: Wc2 row f = [Wr2(128) | Wl2(128)]
    if (idx < 128 * 256) {
        int f = idx >> 8, k = idx & 255;
        float v = (k < 128) ? Wr2[f * 128 + k] : Wl2[f * 128 + (k - 128)];
        Wc2[idx] = f2bf(v);
    }
    // job D: graph starts from sorted batch
    if (idx < N_NODES) {
        int b = batch[idx];
        int pb = (idx == 0) ? -1 : batch[idx - 1];
        for (int g = pb + 1; g <= b; ++g) starts[g] = idx;
        if (idx == N_NODES - 1)
            for (int g = b + 1; g <= N_GRAPHS; ++g) starts[g] = N_NODES;
    }
}

// ---------------------------------------------------------------------------
// agg: wave per node (4/block). DHALF = row width (64 or 128 bf16).
// NG-lane groups each gather one edge, 16 edges in flight per iter.
template <int DHALF>
__global__ __launch_bounds__(256) void agg_kernel(const int* __restrict__ cnt,
                                                  const unsigned short* __restrict__ adj,
                                                  const unsigned short* __restrict__ Xh,
                                                  unsigned short* __restrict__ M)
{
    constexpr int CH = DHALF / 8;    // uint4 chunks per row (8 or 16)
    constexpr int NG = 64 / CH;      // edge groups per wave (8 or 4)
    constexpr int NL = 16 / NG;      // loads per lane per 16-edge iter (2 or 4)
    int n = blockIdx.x * 4 + (threadIdx.x >> 6);
    if (n >= N_NODES) return;
    const int lane = threadIdx.x & 63;
    const int grp = lane / CH;
    const int sl  = lane % CH;
    int degT = cnt[n];
    int deg  = (degT < CAP) ? degT : CAP;
    int er = (int)adj[(size_t)n * CAP + lane];
    float a0=0.f,a1=0.f,a2=0.f,a3=0.f,a4=0.f,a5=0.f,a6=0.f,a7=0.f;
    const uint4* gbase = (const uint4*)Xh;
    const int c1 = deg - 1;
    for (int e = 0; e < deg; e += 16) {
        uint4 v[NL]; float mk[NL];
        #pragma unroll
        for (int j = 0; j < NL; ++j) {
            int ee = e + j * NG + grp;
            int s = __shfl(er, (ee < c1) ? ee : c1);
            v[j]  = gbase[(size_t)s * CH + sl];
            mk[j] = (ee < deg) ? 1.f : 0.f;
        }
        #pragma unroll
        for (int j = 0; j < NL; ++j) {
            a0 += mk[j] * bflo(v[j].x); a1 += mk[j] * bfhi(v[j].x);
            a2 += mk[j] * bflo(v[j].y); a3 += mk[j] * bfhi(v[j].y);
            a4 += mk[j] * bflo(v[j].z); a5 += mk[j] * bfhi(v[j].z);
            a6 += mk[j] * bflo(v[j].w); a7 += mk[j] * bfhi(v[j].w);
        }
    }
    #pragma unroll
    for (int m = CH; m <= 32; m <<= 1) {
        a0 += __shfl_xor(a0, m); a1 += __shfl_xor(a1, m);
        a2 += __shfl_xor(a2, m); a3 += __shfl_xor(a3, m);
        a4 += __shfl_xor(a4, m); a5 += __shfl_xor(a5, m);
        a6 += __shfl_xor(a6, m); a7 += __shfl_xor(a7, m);
    }
    if (grp == 0) {
        float inv = (degT > 0) ? 1.f / (float)degT : 0.f;
        uint4 p;
        p.x = (unsigned int)f2bf(a0 * inv) | ((unsigned int)f2bf(a1 * inv) << 16);
        p.y = (unsigned int)f2bf(a2 * inv) | ((unsigned int)f2bf(a3 * inv) << 16);
        p.z = (unsigned int)f2bf(a4 * inv) | ((unsigned int)f2bf(a5 * inv) << 16);
        p.w = (unsigned int)f2bf(a6 * inv) | ((unsigned int)f2bf(a7 * inv) << 16);
        ((uint4*)M)[(size_t)n * CH + sl] = p;
    }
}

// ---------------------------------------------------------------------------
// MFMA layer: Out[node][f] = relu(LN([Xh|M] @ Wcat^T + bl)) as bf16
// A: h half from Xh [N][DHALF], mean half from M [N][DHALF]
template <int KPAD>
__global__ __launch_bounds__(256) void mfma_layer_kernel(
    const unsigned short* __restrict__ Xh, const unsigned short* __restrict__ M,
    const unsigned short* __restrict__ W,
    const float* __restrict__ bl, const float* __restrict__ g,
    const float* __restrict__ beta,
    unsigned short* __restrict__ Out)
{
    constexpr int DHALF = KPAD / 2;
    const int lane = threadIdx.x & 63;
    const int wv   = threadIdx.x >> 6;
    const int l15  = lane & 15;
    const int l4   = lane >> 4;
    const int row0 = blockIdx.x * 128 + wv * 32;

    int rA0 = row0 + l15;       if (rA0 > N_NODES - 1) rA0 = N_NODES - 1;
    int rA1 = row0 + 16 + l15;  if (rA1 > N_NODES - 1) rA1 = N_NODES - 1;

    f32x4 acc[2][8];
    #pragma unroll
    for (int m = 0; m < 2; ++m)
        #pragma unroll
        for (int n = 0; n < 8; ++n) acc[m][n] = (f32x4){0.f, 0.f, 0.f, 0.f};

    const int kb = l4 * 8;
    #pragma unroll
    for (int ks = 0; ks < KPAD / 32; ++ks) {
        const int k = ks * 32 + kb;
        bf16x8 a0, a1;
        if (ks < DHALF / 32) {
            a0 = *(const bf16x8*)(Xh + (size_t)rA0 * DHALF + k);
            a1 = *(const bf16x8*)(Xh + (size_t)rA1 * DHALF + k);
        } else {
            a0 = *(const bf16x8*)(M + (size_t)rA0 * DHALF + (k - DHALF));
            a1 = *(const bf16x8*)(M + (size_t)rA1 * DHALF + (k - DHALF));
        }
        #pragma unroll
        for (int ni = 0; ni < 8; ++ni) {
            bf16x8 b = *(const bf16x8*)(W + (size_t)(ni * 16 + l15) * KPAD + k);
            acc[0][ni] = __builtin_amdgcn_mfma_f32_16x16x32_bf16(a0, b, acc[0][ni], 0, 0, 0);
            acc[1][ni] = __builtin_amdgcn_mfma_f32_16x16x32_bf16(a1, b, acc[1][ni], 0, 0, 0);
        }
    }

    float blv[8], gv[8], bev[8];
    #pragma unroll
    for (int ni = 0; ni < 8; ++ni) {
        int f = ni * 16 + l15;
        blv[ni] = bl[f]; gv[ni] = g[f]; bev[ni] = beta[f];
    }

    #pragma unroll
    for (int mi = 0; mi < 2; ++mi) {
        #pragma unroll
        for (int r = 0; r < 4; ++r) {
            float v[8];
            float s1 = 0.f, s2 = 0.f;
            #pragma unroll
            for (int ni = 0; ni < 8; ++ni) {
                float t = acc[mi][ni][r] + blv[ni];
                v[ni] = t; s1 += t; s2 += t * t;
            }
            #pragma unroll
            for (int m = 8; m >= 1; m >>= 1) {
                s1 += __shfl_xor(s1, m);
                s2 += __shfl_xor(s2, m);
            }
            float mu   = s1 * (1.f / 128.f);
            float var  = s2 * (1.f / 128.f) - mu * mu;
            float rstd = rsqrtf(var + LN_EPS);
            int node = row0 + mi * 16 + l4 * 4 + r;
            if (node < N_NODES) {
                #pragma unroll
                for (int ni = 0; ni < 8; ++ni) {
                    float o = gv[ni] * (v[ni] - mu) * rstd + bev[ni];
                    o = fmaxf(o, 0.f);
                    Out[(size_t)node * 128 + ni * 16 + l15] = f2bf(o);
                }
            }
        }
    }
}

// ---------------------------------------------------------------------------
// fused pooling (mean+max) + linear head. 1 block / graph, 256 threads.
__global__ __launch_bounds__(256) void poolhead_kernel(const unsigned short* __restrict__ h2,
                                                       const int* __restrict__ starts,
                                                       const float* __restrict__ Wlin,
                                                       const float* __restrict__ blin,
                                                       float* __restrict__ out)
{
    const int g  = blockIdx.x;
    const int j2 = threadIdx.x & 63;   // col pair 2*j2, 2*j2+1
    const int h  = threadIdx.x >> 6;   // row group 0..3
    const int s0 = starts[g], s1 = starts[g + 1];
    float sa = 0.f, sb = 0.f, ma = -INFINITY, mb = -INFINITY;
    const unsigned int* base = (const unsigned int*)h2;   // row stride 64 uints
    int n = s0 + h;
    for (; n + 4 < s1; n += 8) {
        unsigned int u0 = base[(size_t)n * 64 + j2];
        unsigned int u1 = base[(size_t)(n + 4) * 64 + j2];
        float l0 = bflo(u0), h0 = bfhi(u0);
        float l1 = bflo(u1), h1 = bfhi(u1);
        sa += l0 + l1; sb += h0 + h1;
        ma = fmaxf(ma, fmaxf(l0, l1));
        mb = fmaxf(mb, fmaxf(h0, h1));
    }
    if (n < s1) {
        unsigned int u = base[(size_t)n * 64 + j2];
        float lo = bflo(u), hi = bfhi(u);
        sa += lo; sb += hi;
        ma = fmaxf(ma, lo); mb = fmaxf(mb, hi);
    }
    __shared__ float red[4][4][64];
    __shared__ float pooled[256];
    red[h][0][j2] = sa; red[h][1][j2] = sb; red[h][2][j2] = ma; red[h][3][j2] = mb;
    __syncthreads();
    if (h == 0) {
        #pragma unroll
        for (int o = 1; o < 4; ++o) {
            sa += red[o][0][j2]; sb += red[o][1][j2];
            ma = fmaxf(ma, red[o][2][j2]); mb = fmaxf(mb, red[o][3][j2]);
        }
        int c = s1 - s0;
        float inv = (c > 0) ? 1.f / (float)c : 0.f;
        pooled[2 * j2]           = sa * inv;
        pooled[2 * j2 + 1]       = sb * inv;
        pooled[128 + 2 * j2]     = (c > 0) ? ma : 0.f;
        pooled[128 + 2 * j2 + 1] = (c > 0) ? mb : 0.f;
    }
    __syncthreads();
    if (threadIdx.x < 10) {
        const float* w = Wlin + threadIdx.x * 256;
        float acc = blin[threadIdx.x];
        for (int k = 0; k < 256; ++k) acc += pooled[k] * w[k];
        out[g * 10 + threadIdx.x] = acc;
    }
}

// ---------------------------------------------------------------------------
extern "C" void kernel_launch(void* const* d_in, const int* in_sizes, int n_in,
                              void* d_out, int out_size, void* d_ws, size_t ws_size,
                              hipStream_t stream)
{
    const float* x      = (const float*)d_in[0];
    const float* xdims  = (const float*)d_in[1];
    const int*   stt    = (const int*)d_in[2];
    const int*   eidx   = (const int*)d_in[3];
    const int*   batch  = (const int*)d_in[4];
    const float* st_emb = (const float*)d_in[5];
    const float* Wl1 = (const float*)d_in[6];
    const float* bl1 = (const float*)d_in[7];
    const float* Wr1 = (const float*)d_in[8];
    const float* g1  = (const float*)d_in[9];
    const float* be1 = (const float*)d_in[10];
    const float* Wl2 = (const float*)d_in[11];
    const float* bl2 = (const float*)d_in[12];
    const float* Wr2 = (const float*)d_in[13];
    const float* g2  = (const float*)d_in[14];
    const float* be2 = (const float*)d_in[15];
    const float* Wlin = (const float*)d_in[16];
    const float* blin = (const float*)d_in[17];
    float* out = (float*)d_out;

    const int* esrc_in = eidx;
    const int* edst_in = eidx + N_EDGES;

    char* ws = (char*)d_ws;
    size_t o = 0;
    auto carve = [&](size_t bytes) { void* p = ws + o; o = (o + bytes + 255) & ~(size_t)255; return p; };
    unsigned short* Xh1  = (unsigned short*)carve((size_t)N_NODES * 64 * 2);
    unsigned short* M1   = (unsigned short*)carve((size_t)N_NODES * 64 * 2);
    unsigned short* Xh2  = (unsigned short*)carve((size_t)N_NODES * 128 * 2);
    unsigned short* M2   = (unsigned short*)carve((size_t)N_NODES * 128 * 2);
    unsigned short* h2bf = (unsigned short*)carve((size_t)N_NODES * 128 * 2);
    unsigned short* Wc1  = (unsigned short*)carve((size_t)128 * 128 * 2);
    unsigned short* Wc2  = (unsigned short*)carve((size_t)128 * 256 * 2);
    int*            cnt  = (int*)carve((size_t)N_NODES * 4);
    unsigned short* adj  = (unsigned short*)carve((size_t)N_NODES * CAP * 2);
    int*          starts = (int*)carve((size_t)(N_GRAPHS + 1) * 4);
    (void)ws_size;

    // 1. zero degree counters
    zero_kernel<<<(N_NODES + 255) / 256, 256, 0, stream>>>(cnt);

    // 2. fused edge fill + Xh1 + weight concat + graph starts
    prep_fill_kernel<<<EDGE_BLOCKS + PREP_BLOCKS, 256, 0, stream>>>(
        x, xdims, stt, st_emb, Wl1, Wr1, Wl2, Wr2, batch,
        esrc_in, edst_in, Xh1, Wc1, Wc2, cnt, adj, starts);

    // 3-4. layer 1
    agg_kernel<64><<<(N_NODES + 3) / 4, 256, 0, stream>>>(cnt, adj, Xh1, M1);
    mfma_layer_kernel<128><<<(N_NODES + 127) / 128, 256, 0, stream>>>(
        Xh1, M1, Wc1, bl1, g1, be1, Xh2);

    // 5-6. layer 2
    agg_kernel<128><<<(N_NODES + 3) / 4, 256, 0, stream>>>(cnt, adj, Xh2, M2);
    mfma_layer_kernel<256><<<(N_NODES + 127) / 128, 256, 0, stream>>>(
        Xh2, M2, Wc2, bl2, g2, be2, h2bf);

    // 7. fused pooling + head
    poolhead_kernel<<<N_GRAPHS, 256, 0, stream>>>(h2bf, starts, Wlin, blin, out);
}

// Round 10
// 131.932 us; speedup vs baseline: 1.1896x; 1.0260x over previous
//
#include <hip/hip_runtime.h>
#include <hip/hip_bf16.h>
#include <math.h>

#define N_NODES 50000
#define N_EDGES 600000
#define N_GRAPHS 512
#define LN_EPS 1e-5f
#define CAP 64
#define CSTRIDE 16   // cnt padded: one counter per 64B line
#define EDGE_BLOCKS ((N_EDGES / 4 + 255) / 256)
#define PREP_BLOCKS ((N_NODES * 8 + 255) / 256)

typedef short bf16x8 __attribute__((ext_vector_type(8)));
typedef float f32x4 __attribute__((ext_vector_type(4)));

__device__ __forceinline__ unsigned short f2bf(float f) {
    unsigned int x = __float_as_uint(f);
    return (unsigned short)((x + 0x7fffu + ((x >> 16) & 1u)) >> 16);
}
__device__ __forceinline__ float bflo(unsigned int u) { return __uint_as_float(u << 16); }
__device__ __forceinline__ float bfhi(unsigned int u) { return __uint_as_float(u & 0xffff0000u); }

// ---------------------------------------------------------------------------
__global__ __launch_bounds__(256) void zero_kernel(int* __restrict__ cntp)
{
    int i = blockIdx.x * 256 + threadIdx.x;
    if (i < N_NODES * CSTRIDE) cntp[i] = 0;
}

// ---------------------------------------------------------------------------
// fused: edge->padded-adjacency fill (ushort slots, 4 edges/thread, padded
//        counters)  + Xh1 build (uint4 stores)  + weight concat  + starts
__global__ __launch_bounds__(256) void prep_fill_kernel(
    const float* __restrict__ x, const float* __restrict__ xdims,
    const int* __restrict__ stt, const float* __restrict__ st_emb,
    const float* __restrict__ Wl1, const float* __restrict__ Wr1,
    const float* __restrict__ Wl2, const float* __restrict__ Wr2,
    const int* __restrict__ batch,
    const int* __restrict__ esrc_in, const int* __restrict__ edst_in,
    unsigned short* __restrict__ Xh1, unsigned short* __restrict__ Wc1,
    unsigned short* __restrict__ Wc2, int* __restrict__ cntp,
    unsigned short* __restrict__ adj, int* __restrict__ starts)
{
    if (blockIdx.x < EDGE_BLOCKS) {
        int t = blockIdx.x * 256 + threadIdx.x;
        int e4 = t * 4;
        if (e4 < N_EDGES) {
            int4 d4 = *(const int4*)(edst_in + e4);
            int4 s4 = *(const int4*)(esrc_in + e4);
            int sl0 = atomicAdd(&cntp[d4.x * CSTRIDE], 1);
            int sl1 = atomicAdd(&cntp[d4.y * CSTRIDE], 1);
            int sl2 = atomicAdd(&cntp[d4.z * CSTRIDE], 1);
            int sl3 = atomicAdd(&cntp[d4.w * CSTRIDE], 1);
            if (sl0 < CAP) adj[(size_t)d4.x * CAP + sl0] = (unsigned short)s4.x;
            if (sl1 < CAP) adj[(size_t)d4.y * CAP + sl1] = (unsigned short)s4.y;
            if (sl2 < CAP) adj[(size_t)d4.z * CAP + sl2] = (unsigned short)s4.z;
            if (sl3 < CAP) adj[(size_t)d4.w * CAP + sl3] = (unsigned short)s4.w;
        }
        return;
    }
    int idx = (blockIdx.x - EDGE_BLOCKS) * 256 + threadIdx.x;

    // job A: Xh1[n][c], 8 cols/thread, one uint4 store
    if (idx < N_NODES * 8) {
        int n = idx >> 3;
        int c0 = (idx & 7) * 8;
        float vv[8];
        #pragma unroll
        for (int j = 0; j < 8; ++j) {
            int c = c0 + j;
            float v;
            if (c < 29)       v = x[n * 29 + c];
            else if (c < 32)  v = xdims[n * 3 + (c - 29)];
            else if (c < 44)  v = st_emb[stt[n] * 12 + (c - 32)];
            else              v = 0.f;
            vv[j] = v;
        }
        uint4 p;
        p.x = (unsigned int)f2bf(vv[0]) | ((unsigned int)f2bf(vv[1]) << 16);
        p.y = (unsigned int)f2bf(vv[2]) | ((unsigned int)f2bf(vv[3]) << 16);
        p.z = (unsigned int)f2bf(vv[4]) | ((unsigned int)f2bf(vv[5]) << 16);
        p.w = (unsigned int)f2bf(vv[6]) | ((unsigned int)f2bf(vv[7]) << 16);
        ((uint4*)Xh1)[idx] = p;
    }
    // job B: Wc1 row f = [Wr1(44) | 0x20 | Wl1(44) | 0x20]
    if (idx < 128 * 128) {
        int f = idx >> 7, k = idx & 127;
        float v;
        if (k < 44)        v = Wr1[f * 44 + k];
        else if (k < 64)   v = 0.f;
        else if (k < 108)  v = Wl1[f * 44 + (k - 64)];
        else               v = 0.f;
        Wc1[idx] = f2bf(v);
    }
    // job C: Wc2 row f = [Wr2(128) | Wl2(128)]
    if (idx < 128 * 256) {
        int f = idx >> 8, k = idx & 255;
        float v = (k < 128) ? Wr2[f * 128 + k] : Wl2[f * 128 + (k - 128)];
        Wc2[idx] = f2bf(v);
    }
    // job D: graph starts from sorted batch
    if (idx < N_NODES) {
        int b = batch[idx];
        int pb = (idx == 0) ? -1 : batch[idx - 1];
        for (int g = pb + 1; g <= b; ++g) starts[g] = idx;
        if (idx == N_NODES - 1)
            for (int g = b + 1; g <= N_GRAPHS; ++g) starts[g] = N_NODES;
    }
}

// ---------------------------------------------------------------------------
// agg: wave per node (4/block). DHALF = row width (64 or 128 bf16).
template <int DHALF>
__global__ __launch_bounds__(256) void agg_kernel(const int* __restrict__ cntp,
                                                  const unsigned short* __restrict__ adj,
                                                  const unsigned short* __restrict__ Xh,
                                                  unsigned short* __restrict__ M)
{
    constexpr int CH = DHALF / 8;    // uint4 chunks per row (8 or 16)
    constexpr int NG = 64 / CH;      // edge groups per wave (8 or 4)
    constexpr int NL = 16 / NG;      // loads per lane per 16-edge iter (2 or 4)
    int n = blockIdx.x * 4 + (threadIdx.x >> 6);
    if (n >= N_NODES) return;
    const int lane = threadIdx.x & 63;
    const int grp = lane / CH;
    const int sl  = lane % CH;
    int degT = cntp[n * CSTRIDE];
    int deg  = (degT < CAP) ? degT : CAP;
    int er = (int)adj[(size_t)n * CAP + lane];
    float a0=0.f,a1=0.f,a2=0.f,a3=0.f,a4=0.f,a5=0.f,a6=0.f,a7=0.f;
    const uint4* gbase = (const uint4*)Xh;
    const int c1 = deg - 1;
    for (int e = 0; e < deg; e += 16) {
        uint4 v[NL]; float mk[NL];
        #pragma unroll
        for (int j = 0; j < NL; ++j) {
            int ee = e + j * NG + grp;
            int s = __shfl(er, (ee < c1) ? ee : c1);
            v[j]  = gbase[(size_t)s * CH + sl];
            mk[j] = (ee < deg) ? 1.f : 0.f;
        }
        #pragma unroll
        for (int j = 0; j < NL; ++j) {
            a0 += mk[j] * bflo(v[j].x); a1 += mk[j] * bfhi(v[j].x);
            a2 += mk[j] * bflo(v[j].y); a3 += mk[j] * bfhi(v[j].y);
            a4 += mk[j] * bflo(v[j].z); a5 += mk[j] * bfhi(v[j].z);
            a6 += mk[j] * bflo(v[j].w); a7 += mk[j] * bfhi(v[j].w);
        }
    }
    #pragma unroll
    for (int m = CH; m <= 32; m <<= 1) {
        a0 += __shfl_xor(a0, m); a1 += __shfl_xor(a1, m);
        a2 += __shfl_xor(a2, m); a3 += __shfl_xor(a3, m);
        a4 += __shfl_xor(a4, m); a5 += __shfl_xor(a5, m);
        a6 += __shfl_xor(a6, m); a7 += __shfl_xor(a7, m);
    }
    if (grp == 0) {
        float inv = (degT > 0) ? 1.f / (float)degT : 0.f;
        uint4 p;
        p.x = (unsigned int)f2bf(a0 * inv) | ((unsigned int)f2bf(a1 * inv) << 16);
        p.y = (unsigned int)f2bf(a2 * inv) | ((unsigned int)f2bf(a3 * inv) << 16);
        p.z = (unsigned int)f2bf(a4 * inv) | ((unsigned int)f2bf(a5 * inv) << 16);
        p.w = (unsigned int)f2bf(a6 * inv) | ((unsigned int)f2bf(a7 * inv) << 16);
        ((uint4*)M)[(size_t)n * CH + sl] = p;
    }
}

// ---------------------------------------------------------------------------
// MFMA layer: Out[node][f] = relu(LN([Xh|M] @ Wcat^T + bl)) as bf16
template <int KPAD>
__global__ __launch_bounds__(256) void mfma_layer_kernel(
    const unsigned short* __restrict__ Xh, const unsigned short* __restrict__ M,
    const unsigned short* __restrict__ W,
    const float* __restrict__ bl, const float* __restrict__ g,
    const float* __restrict__ beta,
    unsigned short* __restrict__ Out)
{
    constexpr int DHALF = KPAD / 2;
    const int lane = threadIdx.x & 63;
    const int wv   = threadIdx.x >> 6;
    const int l15  = lane & 15;
    const int l4   = lane >> 4;
    const int row0 = blockIdx.x * 128 + wv * 32;

    int rA0 = row0 + l15;       if (rA0 > N_NODES - 1) rA0 = N_NODES - 1;
    int rA1 = row0 + 16 + l15;  if (rA1 > N_NODES - 1) rA1 = N_NODES - 1;

    f32x4 acc[2][8];
    #pragma unroll
    for (int m = 0; m < 2; ++m)
        #pragma unroll
        for (int n = 0; n < 8; ++n) acc[m][n] = (f32x4){0.f, 0.f, 0.f, 0.f};

    const int kb = l4 * 8;
    #pragma unroll
    for (int ks = 0; ks < KPAD / 32; ++ks) {
        const int k = ks * 32 + kb;
        bf16x8 a0, a1;
        if (ks < DHALF / 32) {
            a0 = *(const bf16x8*)(Xh + (size_t)rA0 * DHALF + k);
            a1 = *(const bf16x8*)(Xh + (size_t)rA1 * DHALF + k);
        } else {
            a0 = *(const bf16x8*)(M + (size_t)rA0 * DHALF + (k - DHALF));
            a1 = *(const bf16x8*)(M + (size_t)rA1 * DHALF + (k - DHALF));
        }
        #pragma unroll
        for (int ni = 0; ni < 8; ++ni) {
            bf16x8 b = *(const bf16x8*)(W + (size_t)(ni * 16 + l15) * KPAD + k);
            acc[0][ni] = __builtin_amdgcn_mfma_f32_16x16x32_bf16(a0, b, acc[0][ni], 0, 0, 0);
            acc[1][ni] = __builtin_amdgcn_mfma_f32_16x16x32_bf16(a1, b, acc[1][ni], 0, 0, 0);
        }
    }

    float blv[8], gv[8], bev[8];
    #pragma unroll
    for (int ni = 0; ni < 8; ++ni) {
        int f = ni * 16 + l15;
        blv[ni] = bl[f]; gv[ni] = g[f]; bev[ni] = beta[f];
    }

    #pragma unroll
    for (int mi = 0; mi < 2; ++mi) {
        #pragma unroll
        for (int r = 0; r < 4; ++r) {
            float v[8];
            float s1 = 0.f, s2 = 0.f;
            #pragma unroll
            for (int ni = 0; ni < 8; ++ni) {
                float t = acc[mi][ni][r] + blv[ni];
                v[ni] = t; s1 += t; s2 += t * t;
            }
            #pragma unroll
            for (int m = 8; m >= 1; m >>= 1) {
                s1 += __shfl_xor(s1, m);
                s2 += __shfl_xor(s2, m);
            }
            float mu   = s1 * (1.f / 128.f);
            float var  = s2 * (1.f / 128.f) - mu * mu;
            float rstd = rsqrtf(var + LN_EPS);
            int node = row0 + mi * 16 + l4 * 4 + r;
            if (node < N_NODES) {
                #pragma unroll
                for (int ni = 0; ni < 8; ++ni) {
                    float o = gv[ni] * (v[ni] - mu) * rstd + bev[ni];
                    o = fmaxf(o, 0.f);
                    Out[(size_t)node * 128 + ni * 16 + l15] = f2bf(o);
                }
            }
        }
    }
}

// ---------------------------------------------------------------------------
// fused pooling (mean+max) + linear head. 1 block / graph, 256 threads.
__global__ __launch_bounds__(256) void poolhead_kernel(const unsigned short* __restrict__ h2,
                                                       const int* __restrict__ starts,
                                                       const float* __restrict__ Wlin,
                                                       const float* __restrict__ blin,
                                                       float* __restrict__ out)
{
    const int g  = blockIdx.x;
    const int j2 = threadIdx.x & 63;   // col pair 2*j2, 2*j2+1
    const int h  = threadIdx.x >> 6;   // row group 0..3
    const int s0 = starts[g], s1 = starts[g + 1];
    float sa = 0.f, sb = 0.f, ma = -INFINITY, mb = -INFINITY;
    const unsigned int* base = (const unsigned int*)h2;   // row stride 64 uints
    int n = s0 + h;
    for (; n + 4 < s1; n += 8) {
        unsigned int u0 = base[(size_t)n * 64 + j2];
        unsigned int u1 = base[(size_t)(n + 4) * 64 + j2];
        float l0 = bflo(u0), h0 = bfhi(u0);
        float l1 = bflo(u1), h1 = bfhi(u1);
        sa += l0 + l1; sb += h0 + h1;
        ma = fmaxf(ma, fmaxf(l0, l1));
        mb = fmaxf(mb, fmaxf(h0, h1));
    }
    if (n < s1) {
        unsigned int u = base[(size_t)n * 64 + j2];
        float lo = bflo(u), hi = bfhi(u);
        sa += lo; sb += hi;
        ma = fmaxf(ma, lo); mb = fmaxf(mb, hi);
    }
    __shared__ float red[4][4][64];
    __shared__ float pooled[256];
    red[h][0][j2] = sa; red[h][1][j2] = sb; red[h][2][j2] = ma; red[h][3][j2] = mb;
    __syncthreads();
    if (h == 0) {
        #pragma unroll
        for (int o = 1; o < 4; ++o) {
            sa += red[o][0][j2]; sb += red[o][1][j2];
            ma = fmaxf(ma, red[o][2][j2]); mb = fmaxf(mb, red[o][3][j2]);
        }
        int c = s1 - s0;
        float inv = (c > 0) ? 1.f / (float)c : 0.f;
        pooled[2 * j2]           = sa * inv;
        pooled[2 * j2 + 1]       = sb * inv;
        pooled[128 + 2 * j2]     = (c > 0) ? ma : 0.f;
        pooled[128 + 2 * j2 + 1] = (c > 0) ? mb : 0.f;
    }
    __syncthreads();
    if (threadIdx.x < 10) {
        const float* w = Wlin + threadIdx.x * 256;
        float acc = blin[threadIdx.x];
        for (int k = 0; k < 256; ++k) acc += pooled[k] * w[k];
        out[g * 10 + threadIdx.x] = acc;
    }
}

// ---------------------------------------------------------------------------
extern "C" void kernel_launch(void* const* d_in, const int* in_sizes, int n_in,
                              void* d_out, int out_size, void* d_ws, size_t ws_size,
                              hipStream_t stream)
{
    const float* x      = (const float*)d_in[0];
    const float* xdims  = (const float*)d_in[1];
    const int*   stt    = (const int*)d_in[2];
    const int*   eidx   = (const int*)d_in[3];
    const int*   batch  = (const int*)d_in[4];
    const float* st_emb = (const float*)d_in[5];
    const float* Wl1 = (const float*)d_in[6];
    const float* bl1 = (const float*)d_in[7];
    const float* Wr1 = (const float*)d_in[8];
    const float* g1  = (const float*)d_in[9];
    const float* be1 = (const float*)d_in[10];
    const float* Wl2 = (const float*)d_in[11];
    const float* bl2 = (const float*)d_in[12];
    const float* Wr2 = (const float*)d_in[13];
    const float* g2  = (const float*)d_in[14];
    const float* be2 = (const float*)d_in[15];
    const float* Wlin = (const float*)d_in[16];
    const float* blin = (const float*)d_in[17];
    float* out = (float*)d_out;

    const int* esrc_in = eidx;
    const int* edst_in = eidx + N_EDGES;

    char* ws = (char*)d_ws;
    size_t o = 0;
    auto carve = [&](size_t bytes) { void* p = ws + o; o = (o + bytes + 255) & ~(size_t)255; return p; };
    unsigned short* Xh1  = (unsigned short*)carve((size_t)N_NODES * 64 * 2);
    unsigned short* M1   = (unsigned short*)carve((size_t)N_NODES * 64 * 2);
    unsigned short* Xh2  = (unsigned short*)carve((size_t)N_NODES * 128 * 2);
    unsigned short* M2   = (unsigned short*)carve((size_t)N_NODES * 128 * 2);
    unsigned short* h2bf = (unsigned short*)carve((size_t)N_NODES * 128 * 2);
    unsigned short* Wc1  = (unsigned short*)carve((size_t)128 * 128 * 2);
    unsigned short* Wc2  = (unsigned short*)carve((size_t)128 * 256 * 2);
    int*            cntp = (int*)carve((size_t)N_NODES * CSTRIDE * 4);
    unsigned short* adj  = (unsigned short*)carve((size_t)N_NODES * CAP * 2);
    int*          starts = (int*)carve((size_t)(N_GRAPHS + 1) * 4);
    (void)ws_size;

    // 1. zero padded degree counters
    zero_kernel<<<(N_NODES * CSTRIDE + 255) / 256, 256, 0, stream>>>(cntp);

    // 2. fused edge fill + Xh1 + weight concat + graph starts
    prep_fill_kernel<<<EDGE_BLOCKS + PREP_BLOCKS, 256, 0, stream>>>(
        x, xdims, stt, st_emb, Wl1, Wr1, Wl2, Wr2, batch,
        esrc_in, edst_in, Xh1, Wc1, Wc2, cntp, adj, starts);

    // 3-4. layer 1
    agg_kernel<64><<<(N_NODES + 3) / 4, 256, 0, stream>>>(cntp, adj, Xh1, M1);
    mfma_layer_kernel<128><<<(N_NODES + 127) / 128, 256, 0, stream>>>(
        Xh1, M1, Wc1, bl1, g1, be1, Xh2);

    // 5-6. layer 2
    agg_kernel<128><<<(N_NODES + 3) / 4, 256, 0, stream>>>(cntp, adj, Xh2, M2);
    mfma_layer_kernel<256><<<(N_NODES + 127) / 128, 256, 0, stream>>>(
        Xh2, M2, Wc2, bl2, g2, be2, h2bf);

    // 7. fused pooling + head
    poolhead_kernel<<<N_GRAPHS, 256, 0, stream>>>(h2bf, starts, Wlin, blin, out);
}

// Round 11
// 116.104 us; speedup vs baseline: 1.3517x; 1.1363x over previous
//
#include <hip/hip_runtime.h>
#include <hip/hip_bf16.h>
#include <math.h>

#define N_NODES 50000
#define N_EDGES 600000
#define N_GRAPHS 512
#define LN_EPS 1e-5f
#define CAP 64
#define NPB 128                    // nodes per bin
#define NBINS ((N_NODES + NPB - 1) / NPB)   // 391
#define BCAP 2048                  // edges per bin bucket (E[deg]=1535, +13 sigma)
#define BPAD 16                    // bin counter padding (64B line each)
#define PREP_BLOCKS ((N_NODES * 8 + 255) / 256)

typedef short bf16x8 __attribute__((ext_vector_type(8)));
typedef float f32x4 __attribute__((ext_vector_type(4)));

__device__ __forceinline__ unsigned short f2bf(float f) {
    unsigned int x = __float_as_uint(f);
    return (unsigned short)((x + 0x7fffu + ((x >> 16) & 1u)) >> 16);
}
__device__ __forceinline__ float bflo(unsigned int u) { return __uint_as_float(u << 16); }
__device__ __forceinline__ float bfhi(unsigned int u) { return __uint_as_float(u & 0xffff0000u); }

// ---------------------------------------------------------------------------
// prep: Xh1 build (uint4 stores) + weight concat + starts + binCnt zero
__global__ __launch_bounds__(256) void prep_kernel(
    const float* __restrict__ x, const float* __restrict__ xdims,
    const int* __restrict__ stt, const float* __restrict__ st_emb,
    const float* __restrict__ Wl1, const float* __restrict__ Wr1,
    const float* __restrict__ Wl2, const float* __restrict__ Wr2,
    const int* __restrict__ batch,
    unsigned short* __restrict__ Xh1, unsigned short* __restrict__ Wc1,
    unsigned short* __restrict__ Wc2, int* __restrict__ binCnt,
    int* __restrict__ starts)
{
    int idx = blockIdx.x * 256 + threadIdx.x;

    // job A: Xh1[n][c], 8 cols/thread, one uint4 store
    if (idx < N_NODES * 8) {
        int n = idx >> 3;
        int c0 = (idx & 7) * 8;
        float vv[8];
        #pragma unroll
        for (int j = 0; j < 8; ++j) {
            int c = c0 + j;
            float v;
            if (c < 29)       v = x[n * 29 + c];
            else if (c < 32)  v = xdims[n * 3 + (c - 29)];
            else if (c < 44)  v = st_emb[stt[n] * 12 + (c - 32)];
            else              v = 0.f;
            vv[j] = v;
        }
        uint4 p;
        p.x = (unsigned int)f2bf(vv[0]) | ((unsigned int)f2bf(vv[1]) << 16);
        p.y = (unsigned int)f2bf(vv[2]) | ((unsigned int)f2bf(vv[3]) << 16);
        p.z = (unsigned int)f2bf(vv[4]) | ((unsigned int)f2bf(vv[5]) << 16);
        p.w = (unsigned int)f2bf(vv[6]) | ((unsigned int)f2bf(vv[7]) << 16);
        ((uint4*)Xh1)[idx] = p;
    }
    // job B: Wc1 row f = [Wr1(44) | 0x20 | Wl1(44) | 0x20]
    if (idx < 128 * 128) {
        int f = idx >> 7, k = idx & 127;
        float v;
        if (k < 44)        v = Wr1[f * 44 + k];
        else if (k < 64)   v = 0.f;
        else if (k < 108)  v = Wl1[f * 44 + (k - 64)];
        else               v = 0.f;
        Wc1[idx] = f2bf(v);
    }
    // job C: Wc2 row f = [Wr2(128) | Wl2(128)]
    if (idx < 128 * 256) {
        int f = idx >> 8, k = idx & 255;
        float v = (k < 128) ? Wr2[f * 128 + k] : Wl2[f * 128 + (k - 128)];
        Wc2[idx] = f2bf(v);
    }
    // job D: graph starts from sorted batch
    if (idx < N_NODES) {
        int b = batch[idx];
        int pb = (idx == 0) ? -1 : batch[idx - 1];
        for (int g = pb + 1; g <= b; ++g) starts[g] = idx;
        if (idx == N_NODES - 1)
            for (int g = b + 1; g <= N_GRAPHS; ++g) starts[g] = N_NODES;
    }
    // job E: zero padded bin counters
    if (idx < NBINS * BPAD) binCnt[idx] = 0;
}

// ---------------------------------------------------------------------------
// P1: scatter edges into per-bin buckets. LDS ranks, ~391 global atomics/block.
__global__ __launch_bounds__(1024) void bin_scatter_kernel(
    const int* __restrict__ esrc_in, const int* __restrict__ edst_in,
    int* __restrict__ binCnt, unsigned int* __restrict__ binBuf)
{
    __shared__ int cntL[NBINS];
    __shared__ int gbaseL[NBINS];
    const int tid = threadIdx.x;
    for (int i = tid; i < NBINS; i += 1024) cntL[i] = 0;
    __syncthreads();

    int e4 = (blockIdx.x * 1024 + tid) * 4;
    int4 d4, s4; int b0=0,b1=0,b2=0,b3=0, r0=0,r1=0,r2=0,r3=0;
    const bool valid = e4 < N_EDGES;
    if (valid) {
        d4 = *(const int4*)(edst_in + e4);
        s4 = *(const int4*)(esrc_in + e4);
        b0 = d4.x >> 7; b1 = d4.y >> 7; b2 = d4.z >> 7; b3 = d4.w >> 7;
        r0 = atomicAdd(&cntL[b0], 1);
        r1 = atomicAdd(&cntL[b1], 1);
        r2 = atomicAdd(&cntL[b2], 1);
        r3 = atomicAdd(&cntL[b3], 1);
    }
    __syncthreads();
    for (int i = tid; i < NBINS; i += 1024) {
        int c = cntL[i];
        gbaseL[i] = (c > 0) ? atomicAdd(&binCnt[i * BPAD], c) : 0;
    }
    __syncthreads();
    if (valid) {
        int p0 = gbaseL[b0] + r0, p1 = gbaseL[b1] + r1;
        int p2 = gbaseL[b2] + r2, p3 = gbaseL[b3] + r3;
        if (p0 < BCAP) binBuf[(size_t)b0 * BCAP + p0] = (((unsigned)d4.x & 127u) << 16) | (unsigned)s4.x;
        if (p1 < BCAP) binBuf[(size_t)b1 * BCAP + p1] = (((unsigned)d4.y & 127u) << 16) | (unsigned)s4.y;
        if (p2 < BCAP) binBuf[(size_t)b2 * BCAP + p2] = (((unsigned)d4.z & 127u) << 16) | (unsigned)s4.z;
        if (p3 < BCAP) binBuf[(size_t)b3 * BCAP + p3] = (((unsigned)d4.w & 127u) << 16) | (unsigned)s4.w;
    }
}

// ---------------------------------------------------------------------------
// P2: per-bin adjacency build. LDS slot counters; stores within 16KB window.
__global__ __launch_bounds__(256) void bin_adj_kernel(
    const int* __restrict__ binCnt, const unsigned int* __restrict__ binBuf,
    unsigned short* __restrict__ adj, int* __restrict__ cnt)
{
    __shared__ int cl[NPB];
    const int b = blockIdx.x;
    const int tid = threadIdx.x;
    if (tid < NPB) cl[tid] = 0;
    __syncthreads();
    int ec = binCnt[b * BPAD]; if (ec > BCAP) ec = BCAP;
    const unsigned int* buf = binBuf + (size_t)b * BCAP;
    for (int i = tid; i < ec; i += 256) {
        unsigned int p = buf[i];
        int dl = (int)(p >> 16);
        int slot = atomicAdd(&cl[dl], 1);
        if (slot < CAP)
            adj[((size_t)(b * NPB + dl)) * CAP + slot] = (unsigned short)(p & 0xFFFFu);
    }
    __syncthreads();
    if (tid < NPB) {
        int n = b * NPB + tid;
        if (n < N_NODES) cnt[n] = cl[tid];
    }
}

// ---------------------------------------------------------------------------
// agg: wave per node (4/block). DHALF = row width (64 or 128 bf16).
template <int DHALF>
__global__ __launch_bounds__(256) void agg_kernel(const int* __restrict__ cnt,
                                                  const unsigned short* __restrict__ adj,
                                                  const unsigned short* __restrict__ Xh,
                                                  unsigned short* __restrict__ M)
{
    constexpr int CH = DHALF / 8;    // uint4 chunks per row (8 or 16)
    constexpr int NG = 64 / CH;      // edge groups per wave (8 or 4)
    constexpr int NL = 16 / NG;      // loads per lane per 16-edge iter (2 or 4)
    int n = blockIdx.x * 4 + (threadIdx.x >> 6);
    if (n >= N_NODES) return;
    const int lane = threadIdx.x & 63;
    const int grp = lane / CH;
    const int sl  = lane % CH;
    int degT = cnt[n];
    int deg  = (degT < CAP) ? degT : CAP;
    int er = (int)adj[(size_t)n * CAP + lane];
    float a0=0.f,a1=0.f,a2=0.f,a3=0.f,a4=0.f,a5=0.f,a6=0.f,a7=0.f;
    const uint4* gbase = (const uint4*)Xh;
    const int c1 = deg - 1;
    for (int e = 0; e < deg; e += 16) {
        uint4 v[NL]; float mk[NL];
        #pragma unroll
        for (int j = 0; j < NL; ++j) {
            int ee = e + j * NG + grp;
            int s = __shfl(er, (ee < c1) ? ee : c1);
            v[j]  = gbase[(size_t)s * CH + sl];
            mk[j] = (ee < deg) ? 1.f : 0.f;
        }
        #pragma unroll
        for (int j = 0; j < NL; ++j) {
            a0 += mk[j] * bflo(v[j].x); a1 += mk[j] * bfhi(v[j].x);
            a2 += mk[j] * bflo(v[j].y); a3 += mk[j] * bfhi(v[j].y);
            a4 += mk[j] * bflo(v[j].z); a5 += mk[j] * bfhi(v[j].z);
            a6 += mk[j] * bflo(v[j].w); a7 += mk[j] * bfhi(v[j].w);
        }
    }
    #pragma unroll
    for (int m = CH; m <= 32; m <<= 1) {
        a0 += __shfl_xor(a0, m); a1 += __shfl_xor(a1, m);
        a2 += __shfl_xor(a2, m); a3 += __shfl_xor(a3, m);
        a4 += __shfl_xor(a4, m); a5 += __shfl_xor(a5, m);
        a6 += __shfl_xor(a6, m); a7 += __shfl_xor(a7, m);
    }
    if (grp == 0) {
        float inv = (degT > 0) ? 1.f / (float)degT : 0.f;
        uint4 p;
        p.x = (unsigned int)f2bf(a0 * inv) | ((unsigned int)f2bf(a1 * inv) << 16);
        p.y = (unsigned int)f2bf(a2 * inv) | ((unsigned int)f2bf(a3 * inv) << 16);
        p.z = (unsigned int)f2bf(a4 * inv) | ((unsigned int)f2bf(a5 * inv) << 16);
        p.w = (unsigned int)f2bf(a6 * inv) | ((unsigned int)f2bf(a7 * inv) << 16);
        ((uint4*)M)[(size_t)n * CH + sl] = p;
    }
}

// ---------------------------------------------------------------------------
// MFMA layer: Out[node][f] = relu(LN([Xh|M] @ Wcat^T + bl)) as bf16
template <int KPAD>
__global__ __launch_bounds__(256) void mfma_layer_kernel(
    const unsigned short* __restrict__ Xh, const unsigned short* __restrict__ M,
    const unsigned short* __restrict__ W,
    const float* __restrict__ bl, const float* __restrict__ g,
    const float* __restrict__ beta,
    unsigned short* __restrict__ Out)
{
    constexpr int DHALF = KPAD / 2;
    const int lane = threadIdx.x & 63;
    const int wv   = threadIdx.x >> 6;
    const int l15  = lane & 15;
    const int l4   = lane >> 4;
    const int row0 = blockIdx.x * 128 + wv * 32;

    int rA0 = row0 + l15;       if (rA0 > N_NODES - 1) rA0 = N_NODES - 1;
    int rA1 = row0 + 16 + l15;  if (rA1 > N_NODES - 1) rA1 = N_NODES - 1;

    f32x4 acc[2][8];
    #pragma unroll
    for (int m = 0; m < 2; ++m)
        #pragma unroll
        for (int n = 0; n < 8; ++n) acc[m][n] = (f32x4){0.f, 0.f, 0.f, 0.f};

    const int kb = l4 * 8;
    #pragma unroll
    for (int ks = 0; ks < KPAD / 32; ++ks) {
        const int k = ks * 32 + kb;
        bf16x8 a0, a1;
        if (ks < DHALF / 32) {
            a0 = *(const bf16x8*)(Xh + (size_t)rA0 * DHALF + k);
            a1 = *(const bf16x8*)(Xh + (size_t)rA1 * DHALF + k);
        } else {
            a0 = *(const bf16x8*)(M + (size_t)rA0 * DHALF + (k - DHALF));
            a1 = *(const bf16x8*)(M + (size_t)rA1 * DHALF + (k - DHALF));
        }
        #pragma unroll
        for (int ni = 0; ni < 8; ++ni) {
            bf16x8 b = *(const bf16x8*)(W + (size_t)(ni * 16 + l15) * KPAD + k);
            acc[0][ni] = __builtin_amdgcn_mfma_f32_16x16x32_bf16(a0, b, acc[0][ni], 0, 0, 0);
            acc[1][ni] = __builtin_amdgcn_mfma_f32_16x16x32_bf16(a1, b, acc[1][ni], 0, 0, 0);
        }
    }

    float blv[8], gv[8], bev[8];
    #pragma unroll
    for (int ni = 0; ni < 8; ++ni) {
        int f = ni * 16 + l15;
        blv[ni] = bl[f]; gv[ni] = g[f]; bev[ni] = beta[f];
    }

    #pragma unroll
    for (int mi = 0; mi < 2; ++mi) {
        #pragma unroll
        for (int r = 0; r < 4; ++r) {
            float v[8];
            float s1 = 0.f, s2 = 0.f;
            #pragma unroll
            for (int ni = 0; ni < 8; ++ni) {
                float t = acc[mi][ni][r] + blv[ni];
                v[ni] = t; s1 += t; s2 += t * t;
            }
            #pragma unroll
            for (int m = 8; m >= 1; m >>= 1) {
                s1 += __shfl_xor(s1, m);
                s2 += __shfl_xor(s2, m);
            }
            float mu   = s1 * (1.f / 128.f);
            float var  = s2 * (1.f / 128.f) - mu * mu;
            float rstd = rsqrtf(var + LN_EPS);
            int node = row0 + mi * 16 + l4 * 4 + r;
            if (node < N_NODES) {
                #pragma unroll
                for (int ni = 0; ni < 8; ++ni) {
                    float o = gv[ni] * (v[ni] - mu) * rstd + bev[ni];
                    o = fmaxf(o, 0.f);
                    Out[(size_t)node * 128 + ni * 16 + l15] = f2bf(o);
                }
            }
        }
    }
}

// ---------------------------------------------------------------------------
// fused pooling (mean+max) + linear head. 1 block / graph, 256 threads.
__global__ __launch_bounds__(256) void poolhead_kernel(const unsigned short* __restrict__ h2,
                                                       const int* __restrict__ starts,
                                                       const float* __restrict__ Wlin,
                                                       const float* __restrict__ blin,
                                                       float* __restrict__ out)
{
    const int g  = blockIdx.x;
    const int j2 = threadIdx.x & 63;   // col pair 2*j2, 2*j2+1
    const int h  = threadIdx.x >> 6;   // row group 0..3
    const int s0 = starts[g], s1 = starts[g + 1];
    float sa = 0.f, sb = 0.f, ma = -INFINITY, mb = -INFINITY;
    const unsigned int* base = (const unsigned int*)h2;   // row stride 64 uints
    int n = s0 + h;
    for (; n + 4 < s1; n += 8) {
        unsigned int u0 = base[(size_t)n * 64 + j2];
        unsigned int u1 = base[(size_t)(n + 4) * 64 + j2];
        float l0 = bflo(u0), h0 = bfhi(u0);
        float l1 = bflo(u1), h1 = bfhi(u1);
        sa += l0 + l1; sb += h0 + h1;
        ma = fmaxf(ma, fmaxf(l0, l1));
        mb = fmaxf(mb, fmaxf(h0, h1));
    }
    if (n < s1) {
        unsigned int u = base[(size_t)n * 64 + j2];
        float lo = bflo(u), hi = bfhi(u);
        sa += lo; sb += hi;
        ma = fmaxf(ma, lo); mb = fmaxf(mb, hi);
    }
    __shared__ float red[4][4][64];
    __shared__ float pooled[256];
    red[h][0][j2] = sa; red[h][1][j2] = sb; red[h][2][j2] = ma; red[h][3][j2] = mb;
    __syncthreads();
    if (h == 0) {
        #pragma unroll
        for (int o = 1; o < 4; ++o) {
            sa += red[o][0][j2]; sb += red[o][1][j2];
            ma = fmaxf(ma, red[o][2][j2]); mb = fmaxf(mb, red[o][3][j2]);
        }
        int c = s1 - s0;
        float inv = (c > 0) ? 1.f / (float)c : 0.f;
        pooled[2 * j2]           = sa * inv;
        pooled[2 * j2 + 1]       = sb * inv;
        pooled[128 + 2 * j2]     = (c > 0) ? ma : 0.f;
        pooled[128 + 2 * j2 + 1] = (c > 0) ? mb : 0.f;
    }
    __syncthreads();
    if (threadIdx.x < 10) {
        const float* w = Wlin + threadIdx.x * 256;
        float acc = blin[threadIdx.x];
        for (int k = 0; k < 256; ++k) acc += pooled[k] * w[k];
        out[g * 10 + threadIdx.x] = acc;
    }
}

// ---------------------------------------------------------------------------
extern "C" void kernel_launch(void* const* d_in, const int* in_sizes, int n_in,
                              void* d_out, int out_size, void* d_ws, size_t ws_size,
                              hipStream_t stream)
{
    const float* x      = (const float*)d_in[0];
    const float* xdims  = (const float*)d_in[1];
    const int*   stt    = (const int*)d_in[2];
    const int*   eidx   = (const int*)d_in[3];
    const int*   batch  = (const int*)d_in[4];
    const float* st_emb = (const float*)d_in[5];
    const float* Wl1 = (const float*)d_in[6];
    const float* bl1 = (const float*)d_in[7];
    const float* Wr1 = (const float*)d_in[8];
    const float* g1  = (const float*)d_in[9];
    const float* be1 = (const float*)d_in[10];
    const float* Wl2 = (const float*)d_in[11];
    const float* bl2 = (const float*)d_in[12];
    const float* Wr2 = (const float*)d_in[13];
    const float* g2  = (const float*)d_in[14];
    const float* be2 = (const float*)d_in[15];
    const float* Wlin = (const float*)d_in[16];
    const float* blin = (const float*)d_in[17];
    float* out = (float*)d_out;

    const int* esrc_in = eidx;
    const int* edst_in = eidx + N_EDGES;

    char* ws = (char*)d_ws;
    size_t o = 0;
    auto carve = [&](size_t bytes) { void* p = ws + o; o = (o + bytes + 255) & ~(size_t)255; return p; };
    unsigned short* Xh1  = (unsigned short*)carve((size_t)N_NODES * 64 * 2);
    unsigned short* M1   = (unsigned short*)carve((size_t)N_NODES * 64 * 2);
    unsigned short* Xh2  = (unsigned short*)carve((size_t)N_NODES * 128 * 2);
    unsigned short* M2   = (unsigned short*)carve((size_t)N_NODES * 128 * 2);
    unsigned short* h2bf = (unsigned short*)carve((size_t)N_NODES * 128 * 2);
    unsigned short* Wc1  = (unsigned short*)carve((size_t)128 * 128 * 2);
    unsigned short* Wc2  = (unsigned short*)carve((size_t)128 * 256 * 2);
    int*            cnt  = (int*)carve((size_t)N_NODES * 4);
    int*          binCnt = (int*)carve((size_t)NBINS * BPAD * 4);
    unsigned int* binBuf = (unsigned int*)carve((size_t)NBINS * BCAP * 4);
    unsigned short* adj  = (unsigned short*)carve((size_t)(NBINS * NPB) * CAP * 2);
    int*          starts = (int*)carve((size_t)(N_GRAPHS + 1) * 4);
    (void)ws_size;

    // 1. prep: Xh1 + weight concat + starts + binCnt zero
    prep_kernel<<<PREP_BLOCKS, 256, 0, stream>>>(
        x, xdims, stt, st_emb, Wl1, Wr1, Wl2, Wr2, batch,
        Xh1, Wc1, Wc2, binCnt, starts);

    // 2. P1: edges -> per-bin buckets
    bin_scatter_kernel<<<(N_EDGES / 4 + 1023) / 1024, 1024, 0, stream>>>(
        esrc_in, edst_in, binCnt, binBuf);

    // 3. P2: buckets -> padded adjacency + degrees
    bin_adj_kernel<<<NBINS, 256, 0, stream>>>(binCnt, binBuf, adj, cnt);

    // 4-5. layer 1
    agg_kernel<64><<<(N_NODES + 3) / 4, 256, 0, stream>>>(cnt, adj, Xh1, M1);
    mfma_layer_kernel<128><<<(N_NODES + 127) / 128, 256, 0, stream>>>(
        Xh1, M1, Wc1, bl1, g1, be1, Xh2);

    // 6-7. layer 2
    agg_kernel<128><<<(N_NODES + 3) / 4, 256, 0, stream>>>(cnt, adj, Xh2, M2);
    mfma_layer_kernel<256><<<(N_NODES + 127) / 128, 256, 0, stream>>>(
        Xh2, M2, Wc2, bl2, g2, be2, h2bf);

    // 8. fused pooling + head
    poolhead_kernel<<<N_GRAPHS, 256, 0, stream>>>(h2bf, starts, Wlin, blin, out);
}

// Round 12
// 112.462 us; speedup vs baseline: 1.3955x; 1.0324x over previous
//
#include <hip/hip_runtime.h>
#include <hip/hip_bf16.h>
#include <math.h>

#define N_NODES 50000
#define N_EDGES 600000
#define N_GRAPHS 512
#define LN_EPS 1e-5f
#define CAP 64
#define NPB 128                    // nodes per bin
#define NBINS ((N_NODES + NPB - 1) / NPB)   // 391
#define BCAP 2048                  // edges per bin bucket
#define BPAD 16                    // bin counter padding (64B line each)
#define PREP_BLOCKS ((N_NODES * 8 + 255) / 256)

typedef short bf16x8 __attribute__((ext_vector_type(8)));
typedef float f32x4 __attribute__((ext_vector_type(4)));

__device__ __forceinline__ unsigned short f2bf(float f) {
    unsigned int x = __float_as_uint(f);
    return (unsigned short)((x + 0x7fffu + ((x >> 16) & 1u)) >> 16);
}
__device__ __forceinline__ float bflo(unsigned int u) { return __uint_as_float(u << 16); }
__device__ __forceinline__ float bfhi(unsigned int u) { return __uint_as_float(u & 0xffff0000u); }

// ---------------------------------------------------------------------------
// prep: Xh1 build (uint4 stores) + weight concat + starts + binCnt zero
__global__ __launch_bounds__(256) void prep_kernel(
    const float* __restrict__ x, const float* __restrict__ xdims,
    const int* __restrict__ stt, const float* __restrict__ st_emb,
    const float* __restrict__ Wl1, const float* __restrict__ Wr1,
    const float* __restrict__ Wl2, const float* __restrict__ Wr2,
    const int* __restrict__ batch,
    unsigned short* __restrict__ Xh1, unsigned short* __restrict__ Wc1,
    unsigned short* __restrict__ Wc2, int* __restrict__ binCnt,
    int* __restrict__ starts)
{
    int idx = blockIdx.x * 256 + threadIdx.x;

    // job A: Xh1[n][c], 8 cols/thread, one uint4 store
    if (idx < N_NODES * 8) {
        int n = idx >> 3;
        int c0 = (idx & 7) * 8;
        float vv[8];
        #pragma unroll
        for (int j = 0; j < 8; ++j) {
            int c = c0 + j;
            float v;
            if (c < 29)       v = x[n * 29 + c];
            else if (c < 32)  v = xdims[n * 3 + (c - 29)];
            else if (c < 44)  v = st_emb[stt[n] * 12 + (c - 32)];
            else              v = 0.f;
            vv[j] = v;
        }
        uint4 p;
        p.x = (unsigned int)f2bf(vv[0]) | ((unsigned int)f2bf(vv[1]) << 16);
        p.y = (unsigned int)f2bf(vv[2]) | ((unsigned int)f2bf(vv[3]) << 16);
        p.z = (unsigned int)f2bf(vv[4]) | ((unsigned int)f2bf(vv[5]) << 16);
        p.w = (unsigned int)f2bf(vv[6]) | ((unsigned int)f2bf(vv[7]) << 16);
        ((uint4*)Xh1)[idx] = p;
    }
    // job B: Wc1 row f = [Wr1(44) | 0x20 | Wl1(44) | 0x20]
    if (idx < 128 * 128) {
        int f = idx >> 7, k = idx & 127;
        float v;
        if (k < 44)        v = Wr1[f * 44 + k];
        else if (k < 64)   v = 0.f;
        else if (k < 108)  v = Wl1[f * 44 + (k - 64)];
        else               v = 0.f;
        Wc1[idx] = f2bf(v);
    }
    // job C: Wc2 row f = [Wr2(128) | Wl2(128)]
    if (idx < 128 * 256) {
        int f = idx >> 8, k = idx & 255;
        float v = (k < 128) ? Wr2[f * 128 + k] : Wl2[f * 128 + (k - 128)];
        Wc2[idx] = f2bf(v);
    }
    // job D: graph starts from sorted batch
    if (idx < N_NODES) {
        int b = batch[idx];
        int pb = (idx == 0) ? -1 : batch[idx - 1];
        for (int g = pb + 1; g <= b; ++g) starts[g] = idx;
        if (idx == N_NODES - 1)
            for (int g = b + 1; g <= N_GRAPHS; ++g) starts[g] = N_NODES;
    }
    // job E: zero padded bin counters
    if (idx < NBINS * BPAD) binCnt[idx] = 0;
}

// ---------------------------------------------------------------------------
// P1: scatter edges into per-bin buckets. LDS ranks, ~391 global atomics/block.
__global__ __launch_bounds__(1024) void bin_scatter_kernel(
    const int* __restrict__ esrc_in, const int* __restrict__ edst_in,
    int* __restrict__ binCnt, unsigned int* __restrict__ binBuf)
{
    __shared__ int cntL[NBINS];
    __shared__ int gbaseL[NBINS];
    const int tid = threadIdx.x;
    for (int i = tid; i < NBINS; i += 1024) cntL[i] = 0;
    __syncthreads();

    int e4 = (blockIdx.x * 1024 + tid) * 4;
    int4 d4, s4; int b0=0,b1=0,b2=0,b3=0, r0=0,r1=0,r2=0,r3=0;
    const bool valid = e4 < N_EDGES;
    if (valid) {
        d4 = *(const int4*)(edst_in + e4);
        s4 = *(const int4*)(esrc_in + e4);
        b0 = d4.x >> 7; b1 = d4.y >> 7; b2 = d4.z >> 7; b3 = d4.w >> 7;
        r0 = atomicAdd(&cntL[b0], 1);
        r1 = atomicAdd(&cntL[b1], 1);
        r2 = atomicAdd(&cntL[b2], 1);
        r3 = atomicAdd(&cntL[b3], 1);
    }
    __syncthreads();
    for (int i = tid; i < NBINS; i += 1024) {
        int c = cntL[i];
        gbaseL[i] = (c > 0) ? atomicAdd(&binCnt[i * BPAD], c) : 0;
    }
    __syncthreads();
    if (valid) {
        int p0 = gbaseL[b0] + r0, p1 = gbaseL[b1] + r1;
        int p2 = gbaseL[b2] + r2, p3 = gbaseL[b3] + r3;
        if (p0 < BCAP) binBuf[(size_t)b0 * BCAP + p0] = (((unsigned)d4.x & 127u) << 16) | (unsigned)s4.x;
        if (p1 < BCAP) binBuf[(size_t)b1 * BCAP + p1] = (((unsigned)d4.y & 127u) << 16) | (unsigned)s4.y;
        if (p2 < BCAP) binBuf[(size_t)b2 * BCAP + p2] = (((unsigned)d4.z & 127u) << 16) | (unsigned)s4.z;
        if (p3 < BCAP) binBuf[(size_t)b3 * BCAP + p3] = (((unsigned)d4.w & 127u) << 16) | (unsigned)s4.w;
    }
}

// ---------------------------------------------------------------------------
// P2: per-bin adjacency build. LDS slot counters; stores within 16KB window.
__global__ __launch_bounds__(256) void bin_adj_kernel(
    const int* __restrict__ binCnt, const unsigned int* __restrict__ binBuf,
    unsigned short* __restrict__ adj, int* __restrict__ cnt)
{
    __shared__ int cl[NPB];
    const int b = blockIdx.x;
    const int tid = threadIdx.x;
    if (tid < NPB) cl[tid] = 0;
    __syncthreads();
    int ec = binCnt[b * BPAD]; if (ec > BCAP) ec = BCAP;
    const unsigned int* buf = binBuf + (size_t)b * BCAP;
    for (int i = tid; i < ec; i += 256) {
        unsigned int p = buf[i];
        int dl = (int)(p >> 16);
        int slot = atomicAdd(&cl[dl], 1);
        if (slot < CAP)
            adj[((size_t)(b * NPB + dl)) * CAP + slot] = (unsigned short)(p & 0xFFFFu);
    }
    __syncthreads();
    if (tid < NPB) {
        int n = b * NPB + tid;
        if (n < N_NODES) cnt[n] = cl[tid];
    }
}

// ---------------------------------------------------------------------------
// agg: NPW nodes per wave (multiple independent latency chains per wave).
// DHALF = row width in bf16. adj row packed 2 ushorts/lane -> uint shfl.
// Requires N_NODES % (4*NPW) == 0 for exact grids (50000 % 8 == 0, % 16 == 0).
template <int DHALF, int NPW>
__global__ __launch_bounds__(256) void agg_kernel(const int* __restrict__ cnt,
                                                  const unsigned short* __restrict__ adj,
                                                  const unsigned short* __restrict__ Xh,
                                                  unsigned short* __restrict__ M)
{
    constexpr int CH  = DHALF / 8;   // uint4 chunks per row (8 or 16)
    constexpr int LPN = 64 / NPW;    // lanes per node (16 or 32)
    constexpr int NG  = LPN / CH;    // edge groups per node (= 2)
    constexpr int NL  = 16 / NG;     // loads per lane per 16-edge iter (= 8)
    const int lane = threadIdx.x & 63;
    const int wv   = threadIdx.x >> 6;
    const int ln   = lane % LPN;     // lane within node
    const int nbl  = lane - ln;      // node's first lane (shfl base)
    const int grp  = ln / CH;        // 0..NG-1
    const int sl   = ln % CH;        // row chunk
    const int n = (blockIdx.x * 4 + wv) * NPW + (lane / LPN);

    int degT = cnt[n];
    int deg  = (degT < CAP) ? degT : CAP;
    // adj row, 2 edges per lane: covers 2*LPN edges via shfl
    unsigned int er32 = ((const unsigned int*)adj)[(size_t)n * (CAP / 2) + ln];
    float a0=0.f,a1=0.f,a2=0.f,a3=0.f,a4=0.f,a5=0.f,a6=0.f,a7=0.f;
    const uint4* gbase = (const uint4*)Xh;
    const int c1 = deg - 1;
    const int lim1 = (2 * LPN >= CAP) ? deg : ((deg < 2 * LPN) ? deg : 2 * LPN);
    for (int e = 0; e < lim1; e += 16) {
        uint4 v[NL]; float mk[NL];
        #pragma unroll
        for (int j = 0; j < NL; ++j) {
            int ee = e + j * NG + grp;
            int eec = (ee < c1) ? ee : c1;
            unsigned int u = __shfl(er32, nbl + (eec >> 1));
            int s = (eec & 1) ? (int)(u >> 16) : (int)(u & 0xFFFFu);
            v[j]  = gbase[(size_t)s * CH + sl];
            mk[j] = (ee < deg) ? 1.f : 0.f;
        }
        #pragma unroll
        for (int j = 0; j < NL; ++j) {
            a0 += mk[j] * bflo(v[j].x); a1 += mk[j] * bfhi(v[j].x);
            a2 += mk[j] * bflo(v[j].y); a3 += mk[j] * bfhi(v[j].y);
            a4 += mk[j] * bflo(v[j].z); a5 += mk[j] * bfhi(v[j].z);
            a6 += mk[j] * bflo(v[j].w); a7 += mk[j] * bfhi(v[j].w);
        }
    }
    if (2 * LPN < CAP) {            // rare tail (agg1, deg > 32)
        for (int e = 2 * LPN; e < deg; e += 16) {
            uint4 v[NL]; float mk[NL];
            #pragma unroll
            for (int j = 0; j < NL; ++j) {
                int ee = e + j * NG + grp;
                int eec = (ee < c1) ? ee : c1;
                int s = (int)adj[(size_t)n * CAP + eec];
                v[j]  = gbase[(size_t)s * CH + sl];
                mk[j] = (ee < deg) ? 1.f : 0.f;
            }
            #pragma unroll
            for (int j = 0; j < NL; ++j) {
                a0 += mk[j] * bflo(v[j].x); a1 += mk[j] * bfhi(v[j].x);
                a2 += mk[j] * bflo(v[j].y); a3 += mk[j] * bfhi(v[j].y);
                a4 += mk[j] * bflo(v[j].z); a5 += mk[j] * bfhi(v[j].z);
                a6 += mk[j] * bflo(v[j].w); a7 += mk[j] * bfhi(v[j].w);
            }
        }
    }
    // cross-group reduce (NG == 2): partner is lane ^ CH
    a0 += __shfl_xor(a0, CH); a1 += __shfl_xor(a1, CH);
    a2 += __shfl_xor(a2, CH); a3 += __shfl_xor(a3, CH);
    a4 += __shfl_xor(a4, CH); a5 += __shfl_xor(a5, CH);
    a6 += __shfl_xor(a6, CH); a7 += __shfl_xor(a7, CH);

    if (grp == 0) {
        float inv = (degT > 0) ? 1.f / (float)degT : 0.f;
        uint4 p;
        p.x = (unsigned int)f2bf(a0 * inv) | ((unsigned int)f2bf(a1 * inv) << 16);
        p.y = (unsigned int)f2bf(a2 * inv) | ((unsigned int)f2bf(a3 * inv) << 16);
        p.z = (unsigned int)f2bf(a4 * inv) | ((unsigned int)f2bf(a5 * inv) << 16);
        p.w = (unsigned int)f2bf(a6 * inv) | ((unsigned int)f2bf(a7 * inv) << 16);
        ((uint4*)M)[(size_t)n * CH + sl] = p;
    }
}

// ---------------------------------------------------------------------------
// MFMA layer: Out[node][f] = relu(LN([Xh|M] @ Wcat^T + bl)) as bf16
template <int KPAD>
__global__ __launch_bounds__(256) void mfma_layer_kernel(
    const unsigned short* __restrict__ Xh, const unsigned short* __restrict__ M,
    const unsigned short* __restrict__ W,
    const float* __restrict__ bl, const float* __restrict__ g,
    const float* __restrict__ beta,
    unsigned short* __restrict__ Out)
{
    constexpr int DHALF = KPAD / 2;
    const int lane = threadIdx.x & 63;
    const int wv   = threadIdx.x >> 6;
    const int l15  = lane & 15;
    const int l4   = lane >> 4;
    const int row0 = blockIdx.x * 128 + wv * 32;

    int rA0 = row0 + l15;       if (rA0 > N_NODES - 1) rA0 = N_NODES - 1;
    int rA1 = row0 + 16 + l15;  if (rA1 > N_NODES - 1) rA1 = N_NODES - 1;

    f32x4 acc[2][8];
    #pragma unroll
    for (int m = 0; m < 2; ++m)
        #pragma unroll
        for (int n = 0; n < 8; ++n) acc[m][n] = (f32x4){0.f, 0.f, 0.f, 0.f};

    const int kb = l4 * 8;
    #pragma unroll
    for (int ks = 0; ks < KPAD / 32; ++ks) {
        const int k = ks * 32 + kb;
        bf16x8 a0, a1;
        if (ks < DHALF / 32) {
            a0 = *(const bf16x8*)(Xh + (size_t)rA0 * DHALF + k);
            a1 = *(const bf16x8*)(Xh + (size_t)rA1 * DHALF + k);
        } else {
            a0 = *(const bf16x8*)(M + (size_t)rA0 * DHALF + (k - DHALF));
            a1 = *(const bf16x8*)(M + (size_t)rA1 * DHALF + (k - DHALF));
        }
        #pragma unroll
        for (int ni = 0; ni < 8; ++ni) {
            bf16x8 b = *(const bf16x8*)(W + (size_t)(ni * 16 + l15) * KPAD + k);
            acc[0][ni] = __builtin_amdgcn_mfma_f32_16x16x32_bf16(a0, b, acc[0][ni], 0, 0, 0);
            acc[1][ni] = __builtin_amdgcn_mfma_f32_16x16x32_bf16(a1, b, acc[1][ni], 0, 0, 0);
        }
    }

    float blv[8], gv[8], bev[8];
    #pragma unroll
    for (int ni = 0; ni < 8; ++ni) {
        int f = ni * 16 + l15;
        blv[ni] = bl[f]; gv[ni] = g[f]; bev[ni] = beta[f];
    }

    #pragma unroll
    for (int mi = 0; mi < 2; ++mi) {
        #pragma unroll
        for (int r = 0; r < 4; ++r) {
            float v[8];
            float s1 = 0.f, s2 = 0.f;
            #pragma unroll
            for (int ni = 0; ni < 8; ++ni) {
                float t = acc[mi][ni][r] + blv[ni];
                v[ni] = t; s1 += t; s2 += t * t;
            }
            #pragma unroll
            for (int m = 8; m >= 1; m >>= 1) {
                s1 += __shfl_xor(s1, m);
                s2 += __shfl_xor(s2, m);
            }
            float mu   = s1 * (1.f / 128.f);
            float var  = s2 * (1.f / 128.f) - mu * mu;
            float rstd = rsqrtf(var + LN_EPS);
            int node = row0 + mi * 16 + l4 * 4 + r;
            if (node < N_NODES) {
                #pragma unroll
                for (int ni = 0; ni < 8; ++ni) {
                    float o = gv[ni] * (v[ni] - mu) * rstd + bev[ni];
                    o = fmaxf(o, 0.f);
                    Out[(size_t)node * 128 + ni * 16 + l15] = f2bf(o);
                }
            }
        }
    }
}

// ---------------------------------------------------------------------------
// fused pooling (mean+max) + linear head. 1 block / graph, 256 threads.
__global__ __launch_bounds__(256) void poolhead_kernel(const unsigned short* __restrict__ h2,
                                                       const int* __restrict__ starts,
                                                       const float* __restrict__ Wlin,
                                                       const float* __restrict__ blin,
                                                       float* __restrict__ out)
{
    const int g  = blockIdx.x;
    const int j2 = threadIdx.x & 63;   // col pair 2*j2, 2*j2+1
    const int h  = threadIdx.x >> 6;   // row group 0..3
    const int s0 = starts[g], s1 = starts[g + 1];
    float sa = 0.f, sb = 0.f, ma = -INFINITY, mb = -INFINITY;
    const unsigned int* base = (const unsigned int*)h2;   // row stride 64 uints
    int n = s0 + h;
    for (; n + 4 < s1; n += 8) {
        unsigned int u0 = base[(size_t)n * 64 + j2];
        unsigned int u1 = base[(size_t)(n + 4) * 64 + j2];
        float l0 = bflo(u0), h0 = bfhi(u0);
        float l1 = bflo(u1), h1 = bfhi(u1);
        sa += l0 + l1; sb += h0 + h1;
        ma = fmaxf(ma, fmaxf(l0, l1));
        mb = fmaxf(mb, fmaxf(h0, h1));
    }
    if (n < s1) {
        unsigned int u = base[(size_t)n * 64 + j2];
        float lo = bflo(u), hi = bfhi(u);
        sa += lo; sb += hi;
        ma = fmaxf(ma, lo); mb = fmaxf(mb, hi);
    }
    __shared__ float red[4][4][64];
    __shared__ float pooled[256];
    red[h][0][j2] = sa; red[h][1][j2] = sb; red[h][2][j2] = ma; red[h][3][j2] = mb;
    __syncthreads();
    if (h == 0) {
        #pragma unroll
        for (int o = 1; o < 4; ++o) {
            sa += red[o][0][j2]; sb += red[o][1][j2];
            ma = fmaxf(ma, red[o][2][j2]); mb = fmaxf(mb, red[o][3][j2]);
        }
        int c = s1 - s0;
        float inv = (c > 0) ? 1.f / (float)c : 0.f;
        pooled[2 * j2]           = sa * inv;
        pooled[2 * j2 + 1]       = sb * inv;
        pooled[128 + 2 * j2]     = (c > 0) ? ma : 0.f;
        pooled[128 + 2 * j2 + 1] = (c > 0) ? mb : 0.f;
    }
    __syncthreads();
    if (threadIdx.x < 10) {
        const float* w = Wlin + threadIdx.x * 256;
        float acc = blin[threadIdx.x];
        for (int k = 0; k < 256; ++k) acc += pooled[k] * w[k];
        out[g * 10 + threadIdx.x] = acc;
    }
}

// ---------------------------------------------------------------------------
extern "C" void kernel_launch(void* const* d_in, const int* in_sizes, int n_in,
                              void* d_out, int out_size, void* d_ws, size_t ws_size,
                              hipStream_t stream)
{
    const float* x      = (const float*)d_in[0];
    const float* xdims  = (const float*)d_in[1];
    const int*   stt    = (const int*)d_in[2];
    const int*   eidx   = (const int*)d_in[3];
    const int*   batch  = (const int*)d_in[4];
    const float* st_emb = (const float*)d_in[5];
    const float* Wl1 = (const float*)d_in[6];
    const float* bl1 = (const float*)d_in[7];
    const float* Wr1 = (const float*)d_in[8];
    const float* g1  = (const float*)d_in[9];
    const float* be1 = (const float*)d_in[10];
    const float* Wl2 = (const float*)d_in[11];
    const float* bl2 = (const float*)d_in[12];
    const float* Wr2 = (const float*)d_in[13];
    const float* g2  = (const float*)d_in[14];
    const float* be2 = (const float*)d_in[15];
    const float* Wlin = (const float*)d_in[16];
    const float* blin = (const float*)d_in[17];
    float* out = (float*)d_out;

    const int* esrc_in = eidx;
    const int* edst_in = eidx + N_EDGES;

    char* ws = (char*)d_ws;
    size_t o = 0;
    auto carve = [&](size_t bytes) { void* p = ws + o; o = (o + bytes + 255) & ~(size_t)255; return p; };
    unsigned short* Xh1  = (unsigned short*)carve((size_t)N_NODES * 64 * 2);
    unsigned short* M1   = (unsigned short*)carve((size_t)N_NODES * 64 * 2);
    unsigned short* Xh2  = (unsigned short*)carve((size_t)N_NODES * 128 * 2);
    unsigned short* M2   = (unsigned short*)carve((size_t)N_NODES * 128 * 2);
    unsigned short* h2bf = (unsigned short*)carve((size_t)N_NODES * 128 * 2);
    unsigned short* Wc1  = (unsigned short*)carve((size_t)128 * 128 * 2);
    unsigned short* Wc2  = (unsigned short*)carve((size_t)128 * 256 * 2);
    int*            cnt  = (int*)carve((size_t)N_NODES * 4);
    int*          binCnt = (int*)carve((size_t)NBINS * BPAD * 4);
    unsigned int* binBuf = (unsigned int*)carve((size_t)NBINS * BCAP * 4);
    unsigned short* adj  = (unsigned short*)carve((size_t)(NBINS * NPB) * CAP * 2);
    int*          starts = (int*)carve((size_t)(N_GRAPHS + 1) * 4);
    (void)ws_size;

    // 1. prep: Xh1 + weight concat + starts + binCnt zero
    prep_kernel<<<PREP_BLOCKS, 256, 0, stream>>>(
        x, xdims, stt, st_emb, Wl1, Wr1, Wl2, Wr2, batch,
        Xh1, Wc1, Wc2, binCnt, starts);

    // 2. P1: edges -> per-bin buckets
    bin_scatter_kernel<<<(N_EDGES / 4 + 1023) / 1024, 1024, 0, stream>>>(
        esrc_in, edst_in, binCnt, binBuf);

    // 3. P2: buckets -> padded adjacency + degrees
    bin_adj_kernel<<<NBINS, 256, 0, stream>>>(binCnt, binBuf, adj, cnt);

    // 4-5. layer 1 (4 nodes/wave)
    agg_kernel<64, 4><<<N_NODES / 16, 256, 0, stream>>>(cnt, adj, Xh1, M1);
    mfma_layer_kernel<128><<<(N_NODES + 127) / 128, 256, 0, stream>>>(
        Xh1, M1, Wc1, bl1, g1, be1, Xh2);

    // 6-7. layer 2 (2 nodes/wave)
    agg_kernel<128, 2><<<N_NODES / 8, 256, 0, stream>>>(cnt, adj, Xh2, M2);
    mfma_layer_kernel<256><<<(N_NODES + 127) / 128, 256, 0, stream>>>(
        Xh2, M2, Wc2, bl2, g2, be2, h2bf);

    // 8. fused pooling + head
    poolhead_kernel<<<N_GRAPHS, 256, 0, stream>>>(h2bf, starts, Wlin, blin, out);
}